// Round 1
// baseline (406.315 us; speedup 1.0000x reference)
//
#include <hip/hip_runtime.h>
#include <hip/hip_bf16.h>

#define NB 16
#define NN 512
#define NH 8
#define NF 128
#define NEG_SLOPE 0.2f

// ---------------- prep: masked bias + wa vectors ----------------
// mb[i*N+j] = adj ? bias : -1e30
// wasrc[h*128+i] = sum_f W[h,i,f]*a[h,f,0]; wadst same with a[h,128+f,0]
__global__ __launch_bounds__(256) void prep_kernel(
    const int* __restrict__ adj, const float* __restrict__ bias,
    const float* __restrict__ W, const float* __restrict__ a,
    float* __restrict__ mb, float* __restrict__ wasrc, float* __restrict__ wadst)
{
    int t = blockIdx.x * 256 + threadIdx.x;
    if (t < NN * NN) mb[t] = (adj[t] != 0) ? bias[t] : -1.0e30f;
    if (t < NH * NF) {
        int hh = t >> 7, i = t & 127;
        const float* wrow = W + (hh * NF + i) * NF;
        const float* asr = a + hh * 2 * NF;
        const float* ads = asr + NF;
        float s1 = 0.f, s2 = 0.f;
        #pragma unroll 4
        for (int f = 0; f < NF; ++f) {
            float w = wrow[f];
            s1 = fmaf(w, asr[f], s1);
            s2 = fmaf(w, ads[f], s2);
        }
        wasrc[t] = s1; wadst[t] = s2;
    }
}

// ---------------- scores: s_src/s_dst[b,n,h] = h[b,n,:]·wa[h,:] ----------------
__global__ __launch_bounds__(256) void score_kernel(
    const float* __restrict__ h, const float* __restrict__ wasrc,
    const float* __restrict__ wadst, float* __restrict__ ssrc, float* __restrict__ sdst)
{
    __shared__ float wsm[2][NH * (NF + 4)];   // +4 pad: conflict-free across hh
    int tid = threadIdx.x;
    for (int u = tid; u < NH * NF; u += 256) {
        int hh = u >> 7, f = u & 127;
        wsm[0][hh * (NF + 4) + f] = wasrc[u];
        wsm[1][hh * (NF + 4) + f] = wadst[u];
    }
    __syncthreads();
    int t = blockIdx.x * 256 + tid;           // over B*N*H
    int hh = t & 7;
    int bn = t >> 3;
    const float4* hrow = (const float4*)(h + (size_t)bn * NF);
    const float4* w1 = (const float4*)(&wsm[0][hh * (NF + 4)]);
    const float4* w2 = (const float4*)(&wsm[1][hh * (NF + 4)]);
    float s1 = 0.f, s2 = 0.f;
    #pragma unroll
    for (int u = 0; u < NF / 4; ++u) {
        float4 hv = hrow[u], a1 = w1[u], a2 = w2[u];
        s1 += hv.x * a1.x + hv.y * a1.y + hv.z * a1.z + hv.w * a1.w;
        s2 += hv.x * a2.x + hv.y * a2.y + hv.z * a2.z + hv.w * a2.w;
    }
    ssrc[t] = s1; sdst[t] = s2;
}

// ---------------- h_prime GEMM: [8192 x 128] @ [128 x 1024] ----------------
// col = hh*128 + f; W element = W[hh*16384 + k*128 + f]
__global__ __launch_bounds__(256) void hprime_kernel(
    const float* __restrict__ h, const float* __restrict__ W, float* __restrict__ hp)
{
    __shared__ float As[64][NF + 4];   // pad: conflict-free row reads
    __shared__ float Ws[NF][64];
    int tid = threadIdx.x;
    int rowBase = blockIdx.x * 64;     // over B*N
    int colBase = blockIdx.y * 64;     // over H*F
    int hh = colBase >> 7;
    int fbase = colBase & 127;
    {
        int r = tid >> 2, kc = (tid & 3) * 32;
        const float4* src = (const float4*)(h + (size_t)(rowBase + r) * NF + kc);
        #pragma unroll
        for (int u = 0; u < 8; ++u)
            *(float4*)&As[r][kc + 4 * u] = src[u];
    }
    {
        int c = (tid & 15) * 4;
        int k0 = tid >> 4;
        #pragma unroll
        for (int u = 0; u < 8; ++u) {
            int k = k0 + u * 16;
            *(float4*)&Ws[k][c] = *(const float4*)(W + (size_t)(hh * NF + k) * NF + fbase + c);
        }
    }
    __syncthreads();
    int tx = tid & 15, ty = tid >> 4;
    float4 acc0 = {0,0,0,0}, acc1 = {0,0,0,0}, acc2 = {0,0,0,0}, acc3 = {0,0,0,0};
    #pragma unroll 4
    for (int k = 0; k < NF; ++k) {
        float4 wv = *(const float4*)&Ws[k][tx * 4];
        float a0 = As[ty * 4 + 0][k];
        float a1 = As[ty * 4 + 1][k];
        float a2 = As[ty * 4 + 2][k];
        float a3 = As[ty * 4 + 3][k];
        acc0.x = fmaf(a0, wv.x, acc0.x); acc0.y = fmaf(a0, wv.y, acc0.y);
        acc0.z = fmaf(a0, wv.z, acc0.z); acc0.w = fmaf(a0, wv.w, acc0.w);
        acc1.x = fmaf(a1, wv.x, acc1.x); acc1.y = fmaf(a1, wv.y, acc1.y);
        acc1.z = fmaf(a1, wv.z, acc1.z); acc1.w = fmaf(a1, wv.w, acc1.w);
        acc2.x = fmaf(a2, wv.x, acc2.x); acc2.y = fmaf(a2, wv.y, acc2.y);
        acc2.z = fmaf(a2, wv.z, acc2.z); acc2.w = fmaf(a2, wv.w, acc2.w);
        acc3.x = fmaf(a3, wv.x, acc3.x); acc3.y = fmaf(a3, wv.y, acc3.y);
        acc3.z = fmaf(a3, wv.z, acc3.z); acc3.w = fmaf(a3, wv.w, acc3.w);
    }
    int col = colBase + tx * 4;
    int row = rowBase + ty * 4;
    *(float4*)&hp[(size_t)(row + 0) * (NH * NF) + col] = acc0;
    *(float4*)&hp[(size_t)(row + 1) * (NH * NF) + col] = acc1;
    *(float4*)&hp[(size_t)(row + 2) * (NH * NF) + col] = acc2;
    *(float4*)&hp[(size_t)(row + 3) * (NH * NF) + col] = acc3;
}

// ---------------- attention + PV + head-mean ----------------
// block = (itile of 32 rows, head, batch). Softmax wave-per-row; PV 4x4 register
// blocking reading h_prime from global (L2-resident). atomicAdd across heads.
__global__ __launch_bounds__(256) void attn_kernel(
    const float* __restrict__ hp, const float* __restrict__ mb,
    const float* __restrict__ ssrc, const float* __restrict__ sdst,
    float* __restrict__ out)
{
    __shared__ float P[32][NN];   // 64 KB, bank-conflict-free (2-way bcast)
    __shared__ float rs[32];
    int i0 = blockIdx.x * 32;
    int hh = blockIdx.y;
    int b  = blockIdx.z;
    int tid = threadIdx.x;
    int lane = tid & 63, wave = tid >> 6;

    const float* sdst_b = sdst + (size_t)b * NN * NH + hh;   // index by j*NH
    for (int rr = 0; rr < 8; ++rr) {
        int i = wave * 8 + rr;
        int row = i0 + i;
        float s_i = ssrc[((size_t)b * NN + row) * NH + hh];
        const float* mbrow = mb + (size_t)row * NN;
        float e8[8];
        float mx = -3.0e38f;
        #pragma unroll
        for (int v = 0; v < 8; ++v) {
            int j = lane + 64 * v;
            float x = s_i + sdst_b[(size_t)j * NH];
            x = x > 0.f ? x : NEG_SLOPE * x;
            float e = x + mbrow[j];
            e8[v] = e;
            mx = fmaxf(mx, e);
        }
        #pragma unroll
        for (int off = 32; off > 0; off >>= 1) mx = fmaxf(mx, __shfl_xor(mx, off));
        float sum = 0.f;
        #pragma unroll
        for (int v = 0; v < 8; ++v) {
            float p = __expf(e8[v] - mx);
            P[i][lane + 64 * v] = p;
            sum += p;
        }
        #pragma unroll
        for (int off = 32; off > 0; off >>= 1) sum += __shfl_xor(sum, off);
        if (lane == 0) rs[i] = 1.0f / sum;
    }
    __syncthreads();

    int tx = tid & 31, ty = tid >> 5;
    int f0 = tx * 4;
    int r0 = ty * 4;
    const float* hpPanel = hp + (size_t)b * NN * NH * NF + hh * NF + f0;  // + j*(NH*NF)
    float4 acc0 = {0,0,0,0}, acc1 = {0,0,0,0}, acc2 = {0,0,0,0}, acc3 = {0,0,0,0};
    #pragma unroll 4
    for (int j = 0; j < NN; ++j) {
        float4 hv = *(const float4*)(hpPanel + (size_t)j * (NH * NF));
        float p0 = P[r0 + 0][j], p1 = P[r0 + 1][j], p2 = P[r0 + 2][j], p3 = P[r0 + 3][j];
        acc0.x = fmaf(p0, hv.x, acc0.x); acc0.y = fmaf(p0, hv.y, acc0.y);
        acc0.z = fmaf(p0, hv.z, acc0.z); acc0.w = fmaf(p0, hv.w, acc0.w);
        acc1.x = fmaf(p1, hv.x, acc1.x); acc1.y = fmaf(p1, hv.y, acc1.y);
        acc1.z = fmaf(p1, hv.z, acc1.z); acc1.w = fmaf(p1, hv.w, acc1.w);
        acc2.x = fmaf(p2, hv.x, acc2.x); acc2.y = fmaf(p2, hv.y, acc2.y);
        acc2.z = fmaf(p2, hv.z, acc2.z); acc2.w = fmaf(p2, hv.w, acc2.w);
        acc3.x = fmaf(p3, hv.x, acc3.x); acc3.y = fmaf(p3, hv.y, acc3.y);
        acc3.z = fmaf(p3, hv.z, acc3.z); acc3.w = fmaf(p3, hv.w, acc3.w);
    }
    float sc0 = rs[r0 + 0] * 0.125f;
    float sc1 = rs[r0 + 1] * 0.125f;
    float sc2 = rs[r0 + 2] * 0.125f;
    float sc3 = rs[r0 + 3] * 0.125f;
    float* o0 = out + ((size_t)b * NN + i0 + r0 + 0) * NF + f0;
    float* o1 = out + ((size_t)b * NN + i0 + r0 + 1) * NF + f0;
    float* o2 = out + ((size_t)b * NN + i0 + r0 + 2) * NF + f0;
    float* o3 = out + ((size_t)b * NN + i0 + r0 + 3) * NF + f0;
    atomicAdd(o0 + 0, acc0.x * sc0); atomicAdd(o0 + 1, acc0.y * sc0);
    atomicAdd(o0 + 2, acc0.z * sc0); atomicAdd(o0 + 3, acc0.w * sc0);
    atomicAdd(o1 + 0, acc1.x * sc1); atomicAdd(o1 + 1, acc1.y * sc1);
    atomicAdd(o1 + 2, acc1.z * sc1); atomicAdd(o1 + 3, acc1.w * sc1);
    atomicAdd(o2 + 0, acc2.x * sc2); atomicAdd(o2 + 1, acc2.y * sc2);
    atomicAdd(o2 + 2, acc2.z * sc2); atomicAdd(o2 + 3, acc2.w * sc2);
    atomicAdd(o3 + 0, acc3.x * sc3); atomicAdd(o3 + 1, acc3.y * sc3);
    atomicAdd(o3 + 2, acc3.z * sc3); atomicAdd(o3 + 3, acc3.w * sc3);
}

extern "C" void kernel_launch(void* const* d_in, const int* in_sizes, int n_in,
                              void* d_out, int out_size, void* d_ws, size_t ws_size,
                              hipStream_t stream)
{
    const float* h    = (const float*)d_in[0];
    const int*   adj  = (const int*)d_in[1];
    const float* bias = (const float*)d_in[2];
    const float* W    = (const float*)d_in[3];
    const float* a    = (const float*)d_in[4];
    float* out = (float*)d_out;

    float* ws    = (float*)d_ws;
    float* hp    = ws;                                  // B*N*H*F = 8,388,608 f32
    float* mb    = hp + (size_t)NB * NN * NH * NF;      // N*N = 262,144
    float* ssrc  = mb + (size_t)NN * NN;                // B*N*H = 65,536
    float* sdst  = ssrc + (size_t)NB * NN * NH;         // 65,536
    float* wasrc = sdst + (size_t)NB * NN * NH;         // 1,024
    float* wadst = wasrc + NH * NF;                     // 1,024

    hipLaunchKernelGGL(prep_kernel, dim3((NN * NN) / 256), dim3(256), 0, stream,
                       adj, bias, W, a, mb, wasrc, wadst);
    hipLaunchKernelGGL(score_kernel, dim3((NB * NN * NH) / 256), dim3(256), 0, stream,
                       h, wasrc, wadst, ssrc, sdst);
    hipLaunchKernelGGL(hprime_kernel, dim3((NB * NN) / 64, (NH * NF) / 64), dim3(256), 0, stream,
                       h, W, hp);
    hipMemsetAsync(d_out, 0, (size_t)out_size * sizeof(float), stream);
    hipLaunchKernelGGL(attn_kernel, dim3(NN / 32, NH, NB), dim3(256), 0, stream,
                       hp, mb, ssrc, sdst, out);
}

// Round 2
// 193.339 us; speedup vs baseline: 2.1016x; 2.1016x over previous
//
#include <hip/hip_runtime.h>
#include <hip/hip_bf16.h>
#include <string.h>

#define NB 16
#define NN 512
#define NH 8
#define NF 128
#define NEG_SLOPE 0.2f

typedef short bf16x8 __attribute__((ext_vector_type(8)));
typedef float f32x4 __attribute__((ext_vector_type(4)));

__device__ inline unsigned short f2bf(float x) {
    unsigned int u = __float_as_uint(x);
    unsigned int r = (u + 0x7fffu + ((u >> 16) & 1u)) >> 16;   // RNE, finite inputs
    return (unsigned short)r;
}

// ---------------- prep: masked bias + wa vectors ----------------
__global__ __launch_bounds__(256) void prep_kernel(
    const int* __restrict__ adj, const float* __restrict__ bias,
    const float* __restrict__ W, const float* __restrict__ a,
    float* __restrict__ mb, float* __restrict__ wasrc, float* __restrict__ wadst)
{
    int t = blockIdx.x * 256 + threadIdx.x;
    if (t < NN * NN) mb[t] = (adj[t] != 0) ? bias[t] : -1.0e30f;
    if (t < NH * NF) {
        int hh = t >> 7, i = t & 127;
        const float* wrow = W + (hh * NF + i) * NF;
        const float* asr = a + hh * 2 * NF;
        const float* ads = asr + NF;
        float s1 = 0.f, s2 = 0.f;
        #pragma unroll 4
        for (int f = 0; f < NF; ++f) {
            float w = wrow[f];
            s1 = fmaf(w, asr[f], s1);
            s2 = fmaf(w, ads[f], s2);
        }
        wasrc[t] = s1; wadst[t] = s2;
    }
}

// ---------------- scores: f32-exact; sdst stored transposed [b][h][n] ----------------
__global__ __launch_bounds__(256) void score_kernel(
    const float* __restrict__ h, const float* __restrict__ wasrc,
    const float* __restrict__ wadst, float* __restrict__ ssrc, float* __restrict__ sdstT)
{
    __shared__ float wsm[2][NH * (NF + 4)];
    int tid = threadIdx.x;
    for (int u = tid; u < NH * NF; u += 256) {
        int hh = u >> 7, f = u & 127;
        wsm[0][hh * (NF + 4) + f] = wasrc[u];
        wsm[1][hh * (NF + 4) + f] = wadst[u];
    }
    __syncthreads();
    int t = blockIdx.x * 256 + tid;           // over B*N*H
    int hh = t & 7;
    int bn = t >> 3;
    int b = bn >> 9, n = bn & 511;
    const float4* hrow = (const float4*)(h + (size_t)bn * NF);
    const float4* w1 = (const float4*)(&wsm[0][hh * (NF + 4)]);
    const float4* w2 = (const float4*)(&wsm[1][hh * (NF + 4)]);
    float s1 = 0.f, s2 = 0.f;
    #pragma unroll
    for (int u = 0; u < NF / 4; ++u) {
        float4 hv = hrow[u], a1 = w1[u], a2 = w2[u];
        s1 += hv.x * a1.x + hv.y * a1.y + hv.z * a1.z + hv.w * a1.w;
        s2 += hv.x * a2.x + hv.y * a2.y + hv.z * a2.z + hv.w * a2.w;
    }
    ssrc[t] = s1;
    sdstT[((size_t)(b * NH + hh)) * NN + n] = s2;
}

// ---------------- h_prime GEMM (f32 compute) -> bf16 transposed hpT[b][h][f][n] ----------------
__global__ __launch_bounds__(256) void hprime_kernel(
    const float* __restrict__ h, const float* __restrict__ W, unsigned short* __restrict__ hpT)
{
    __shared__ float As[64][NF + 4];
    __shared__ float Ws[NF][64];
    int tid = threadIdx.x;
    int rowBase = blockIdx.x * 64;     // over B*N
    int colBase = blockIdx.y * 64;     // over H*F
    int hh = colBase >> 7;
    int fbase = colBase & 127;
    {
        int r = tid >> 2, kc = (tid & 3) * 32;
        const float4* src = (const float4*)(h + (size_t)(rowBase + r) * NF + kc);
        #pragma unroll
        for (int u = 0; u < 8; ++u)
            *(float4*)&As[r][kc + 4 * u] = src[u];
    }
    {
        int c = (tid & 15) * 4;
        int k0 = tid >> 4;
        #pragma unroll
        for (int u = 0; u < 8; ++u) {
            int k = k0 + u * 16;
            *(float4*)&Ws[k][c] = *(const float4*)(W + (size_t)(hh * NF + k) * NF + fbase + c);
        }
    }
    __syncthreads();
    int tx = tid & 15, ty = tid >> 4;
    float acc[4][4];
    #pragma unroll
    for (int r = 0; r < 4; ++r)
        #pragma unroll
        for (int c = 0; c < 4; ++c) acc[r][c] = 0.f;
    #pragma unroll 4
    for (int k = 0; k < NF; ++k) {
        float4 wv = *(const float4*)&Ws[k][tx * 4];
        float av[4];
        av[0] = As[ty * 4 + 0][k];
        av[1] = As[ty * 4 + 1][k];
        av[2] = As[ty * 4 + 2][k];
        av[3] = As[ty * 4 + 3][k];
        #pragma unroll
        for (int r = 0; r < 4; ++r) {
            acc[r][0] = fmaf(av[r], wv.x, acc[r][0]);
            acc[r][1] = fmaf(av[r], wv.y, acc[r][1]);
            acc[r][2] = fmaf(av[r], wv.z, acc[r][2]);
            acc[r][3] = fmaf(av[r], wv.w, acc[r][3]);
        }
    }
    int b = rowBase >> 9;
    int nInB = (rowBase & 511) + ty * 4;
    #pragma unroll
    for (int cc = 0; cc < 4; ++cc) {
        int f = fbase + tx * 4 + cc;
        ushort4 u;
        u.x = f2bf(acc[0][cc]);
        u.y = f2bf(acc[1][cc]);
        u.z = f2bf(acc[2][cc]);
        u.w = f2bf(acc[3][cc]);
        *(ushort4*)&hpT[((size_t)(b * NH + hh) * NF + f) * NN + nInB] = u;
    }
}

// ---------------- fused attention: softmax + MFMA PV + head-mean in regs ----------------
// 256 blocks (one per CU), 1024 threads. Block = (b, 32-row i-tile), loops 8 heads.
__global__ __launch_bounds__(1024, 4) void attn_kernel(
    const unsigned short* __restrict__ hpT, const float* __restrict__ mb,
    const float* __restrict__ ssrc, const float* __restrict__ sdstT,
    float* __restrict__ out)
{
    __shared__ float mbs[32][NN];                 // 64 KB, reused across 8 heads
    __shared__ unsigned short P[32][NN + 8];      // 33.3 KB, pad -> <=2-way conflicts

    int i0 = (blockIdx.x & 15) * 32;
    int b  = blockIdx.x >> 4;
    int tid = threadIdx.x;
    int lane = tid & 63, wave = tid >> 6;         // 16 waves

    // stage mb tile once
    for (int u = tid; u < 32 * (NN / 4); u += 1024) {
        int r = u >> 7, c4 = (u & 127) * 4;
        *(float4*)&mbs[r][c4] = *(const float4*)&mb[(size_t)(i0 + r) * NN + c4];
    }
    __syncthreads();

    int iGrp = wave >> 3;        // 0..1 -> rows i0w = iGrp*16
    int fch  = wave & 7;         // 0..7 -> cols fch*16
    f32x4 acc0 = {0.f, 0.f, 0.f, 0.f};
    f32x4 acc1 = {0.f, 0.f, 0.f, 0.f};

    for (int hh = 0; hh < NH; ++hh) {
        // ---- softmax: wave handles rows 2*wave, 2*wave+1 ----
        const float* sd = sdstT + ((size_t)(b * NH + hh)) * NN;
        #pragma unroll
        for (int rr = 0; rr < 2; ++rr) {
            int i = wave * 2 + rr;
            int row = i0 + i;
            float s_i = ssrc[((size_t)(b * NN + row)) * NH + hh];
            float p8[8];
            float mx = -3.0e38f;
            #pragma unroll
            for (int v = 0; v < 8; ++v) {
                int j = lane + 64 * v;
                float x = s_i + sd[j];
                x = x > 0.f ? x : NEG_SLOPE * x;
                float e = x + mbs[i][j];
                p8[v] = e;
                mx = fmaxf(mx, e);
            }
            #pragma unroll
            for (int off = 32; off; off >>= 1) mx = fmaxf(mx, __shfl_xor(mx, off));
            float sum = 0.f;
            #pragma unroll
            for (int v = 0; v < 8; ++v) { p8[v] = __expf(p8[v] - mx); sum += p8[v]; }
            #pragma unroll
            for (int off = 32; off; off >>= 1) sum += __shfl_xor(sum, off);
            float rinv = 1.0f / sum;
            #pragma unroll
            for (int v = 0; v < 8; ++v)
                P[i][lane + 64 * v] = f2bf(p8[v] * rinv);
        }
        __syncthreads();

        // ---- PV: wave computes C[iGrp*16..+15][fch*16..+15], K=512 ----
        const unsigned short* Bp = hpT
            + ((size_t)(b * NH + hh) * NF + fch * 16 + (lane & 15)) * NN
            + (lane >> 4) * 8;
        const unsigned short* Ap = &P[iGrp * 16 + (lane & 15)][(lane >> 4) * 8];
        #pragma unroll
        for (int ks = 0; ks < 16; ks += 2) {
            bf16x8 a0 = *(const bf16x8*)(Ap + ks * 32);
            bf16x8 b0 = *(const bf16x8*)(Bp + ks * 32);
            acc0 = __builtin_amdgcn_mfma_f32_16x16x32_bf16(a0, b0, acc0, 0, 0, 0);
            bf16x8 a1 = *(const bf16x8*)(Ap + (ks + 1) * 32);
            bf16x8 b1 = *(const bf16x8*)(Bp + (ks + 1) * 32);
            acc1 = __builtin_amdgcn_mfma_f32_16x16x32_bf16(a1, b1, acc1, 0, 0, 0);
        }
        __syncthreads();   // before next head overwrites P
    }

    // ---- store: f = fch*16 + (lane&15); i = i0 + iGrp*16 + (lane>>4)*4 + r ----
    int f = fch * 16 + (lane & 15);
    int ibase = i0 + iGrp * 16 + (lane >> 4) * 4;
    #pragma unroll
    for (int r = 0; r < 4; ++r)
        out[((size_t)(b * NN + ibase + r)) * NF + f] = (acc0[r] + acc1[r]) * 0.125f;
}

extern "C" void kernel_launch(void* const* d_in, const int* in_sizes, int n_in,
                              void* d_out, int out_size, void* d_ws, size_t ws_size,
                              hipStream_t stream)
{
    const float* h    = (const float*)d_in[0];
    const int*   adj  = (const int*)d_in[1];
    const float* bias = (const float*)d_in[2];
    const float* W    = (const float*)d_in[3];
    const float* a    = (const float*)d_in[4];
    float* out = (float*)d_out;

    unsigned short* hpT = (unsigned short*)d_ws;                    // B*H*F*N bf16 = 16.8 MB
    float* mb    = (float*)(hpT + (size_t)NB * NH * NF * NN);       // N*N
    float* ssrc  = mb + (size_t)NN * NN;                            // B*N*H
    float* sdstT = ssrc + (size_t)NB * NN * NH;                     // B*H*N
    float* wasrc = sdstT + (size_t)NB * NN * NH;
    float* wadst = wasrc + NH * NF;

    hipLaunchKernelGGL(prep_kernel, dim3((NN * NN) / 256), dim3(256), 0, stream,
                       adj, bias, W, a, mb, wasrc, wadst);
    hipLaunchKernelGGL(score_kernel, dim3((NB * NN * NH) / 256), dim3(256), 0, stream,
                       h, wasrc, wadst, ssrc, sdstT);
    hipLaunchKernelGGL(hprime_kernel, dim3((NB * NN) / 64, (NH * NF) / 64), dim3(256), 0, stream,
                       h, W, hpT);
    hipLaunchKernelGGL(attn_kernel, dim3(NB * (NN / 32)), dim3(1024), 0, stream,
                       hpT, mb, ssrc, sdstT, out);
}

// Round 3
// 190.985 us; speedup vs baseline: 2.1275x; 1.0123x over previous
//
#include <hip/hip_runtime.h>
#include <hip/hip_bf16.h>

#define NB 16
#define NN 512
#define NH 8
#define NF 128
#define NEG_SLOPE 0.2f

typedef short bf16x8 __attribute__((ext_vector_type(8)));
typedef unsigned short u16x8 __attribute__((ext_vector_type(8)));
typedef float f32x4 __attribute__((ext_vector_type(4)));

__device__ inline unsigned short f2bf(float x) {
    unsigned int u = __float_as_uint(x);
    unsigned int r = (u + 0x7fffu + ((u >> 16) & 1u)) >> 16;   // RNE, finite inputs
    return (unsigned short)r;
}
__device__ inline float bf2f(unsigned short u) {
    return __uint_as_float(((unsigned int)u) << 16);
}

// ---------------- prep: masked bias + wa vectors ----------------
__global__ __launch_bounds__(256) void prep_kernel(
    const int* __restrict__ adj, const float* __restrict__ bias,
    const float* __restrict__ W, const float* __restrict__ a,
    float* __restrict__ mb, float* __restrict__ wasrc, float* __restrict__ wadst)
{
    int t = blockIdx.x * 256 + threadIdx.x;
    if (t < NN * NN) mb[t] = (adj[t] != 0) ? bias[t] : -1.0e30f;
    if (t < NH * NF) {
        int hh = t >> 7, i = t & 127;
        const float* wrow = W + (hh * NF + i) * NF;
        const float* asr = a + hh * 2 * NF;
        const float* ads = asr + NF;
        float s1 = 0.f, s2 = 0.f;
        #pragma unroll 4
        for (int f = 0; f < NF; ++f) {
            float w = wrow[f];
            s1 = fmaf(w, asr[f], s1);
            s2 = fmaf(w, ads[f], s2);
        }
        wasrc[t] = s1; wadst[t] = s2;
    }
}

// ---------------- split h and W^T into bf16 hi+lo ----------------
__global__ __launch_bounds__(256) void split_kernel(
    const float* __restrict__ h, const float* __restrict__ W,
    unsigned short* __restrict__ hHi, unsigned short* __restrict__ hLo,
    unsigned short* __restrict__ wtHi, unsigned short* __restrict__ wtLo)
{
    int t = blockIdx.x * 256 + threadIdx.x;
    if (t < NB * NN * NF) {
        float v = h[t];
        unsigned short hi = f2bf(v);
        hHi[t] = hi;
        hLo[t] = f2bf(v - bf2f(hi));
    } else {
        int u = t - NB * NN * NF;
        if (u < NH * NF * NF) {
            int fg = u >> 7, k = u & 127;   // fg = hh*128+f
            float v = W[(size_t)(fg >> 7) * NF * NF + k * NF + (fg & 127)];
            unsigned short hi = f2bf(v);
            wtHi[u] = hi;
            wtLo[u] = f2bf(v - bf2f(hi));
        }
    }
}

// ---------------- scores: f32-exact; sdst stored transposed [b][h][n] ----------------
__global__ __launch_bounds__(256) void score_kernel(
    const float* __restrict__ h, const float* __restrict__ wasrc,
    const float* __restrict__ wadst, float* __restrict__ ssrc, float* __restrict__ sdstT)
{
    __shared__ float wsm[2][NH * (NF + 4)];
    int tid = threadIdx.x;
    for (int u = tid; u < NH * NF; u += 256) {
        int hh = u >> 7, f = u & 127;
        wsm[0][hh * (NF + 4) + f] = wasrc[u];
        wsm[1][hh * (NF + 4) + f] = wadst[u];
    }
    __syncthreads();
    int t = blockIdx.x * 256 + tid;           // over B*N*H
    int hh = t & 7;
    int bn = t >> 3;
    int b = bn >> 9, n = bn & 511;
    const float4* hrow = (const float4*)(h + (size_t)bn * NF);
    const float4* w1 = (const float4*)(&wsm[0][hh * (NF + 4)]);
    const float4* w2 = (const float4*)(&wsm[1][hh * (NF + 4)]);
    float s1 = 0.f, s2 = 0.f;
    #pragma unroll
    for (int u = 0; u < NF / 4; ++u) {
        float4 hv = hrow[u], a1 = w1[u], a2 = w2[u];
        s1 += hv.x * a1.x + hv.y * a1.y + hv.z * a1.z + hv.w * a1.w;
        s2 += hv.x * a2.x + hv.y * a2.y + hv.z * a2.z + hv.w * a2.w;
    }
    ssrc[t] = s1;
    sdstT[((size_t)(b * NH + hh)) * NN + n] = s2;
}

// ---------------- h_prime via bf16^3-split MFMA -> hpT[b][hf 1024][n 512] bf16 ----------------
// C[f_global][n_global]; A = Wt (rows f_global, k=128), B = h (rows n_global, k=128).
__global__ __launch_bounds__(256) void hprime_kernel(
    const unsigned short* __restrict__ hHi, const unsigned short* __restrict__ hLo,
    const unsigned short* __restrict__ wtHi, const unsigned short* __restrict__ wtLo,
    unsigned short* __restrict__ hpT)
{
    int tid = threadIdx.x;
    int wave = tid >> 6, lane = tid & 63;
    int col = lane & 15, kg = lane >> 4;
    int f0 = blockIdx.y * 64 + wave * 16;     // f_global tile base (0..1023)
    int n0 = blockIdx.x * 64;                 // n_global base, 4 tiles of 16

    const unsigned short* Ah = wtHi + (size_t)(f0 + col) * NF + kg * 8;
    const unsigned short* Al = wtLo + (size_t)(f0 + col) * NF + kg * 8;
    const unsigned short* Bh0 = hHi + (size_t)(n0 +  0 + col) * NF + kg * 8;
    const unsigned short* Bh1 = hHi + (size_t)(n0 + 16 + col) * NF + kg * 8;
    const unsigned short* Bh2 = hHi + (size_t)(n0 + 32 + col) * NF + kg * 8;
    const unsigned short* Bh3 = hHi + (size_t)(n0 + 48 + col) * NF + kg * 8;
    const unsigned short* Bl0 = hLo + (size_t)(n0 +  0 + col) * NF + kg * 8;
    const unsigned short* Bl1 = hLo + (size_t)(n0 + 16 + col) * NF + kg * 8;
    const unsigned short* Bl2 = hLo + (size_t)(n0 + 32 + col) * NF + kg * 8;
    const unsigned short* Bl3 = hLo + (size_t)(n0 + 48 + col) * NF + kg * 8;

    f32x4 acc0 = {0.f,0.f,0.f,0.f}, acc1 = {0.f,0.f,0.f,0.f};
    f32x4 acc2 = {0.f,0.f,0.f,0.f}, acc3 = {0.f,0.f,0.f,0.f};

    #pragma unroll
    for (int ks = 0; ks < 4; ++ks) {
        int off = ks * 32;
        bf16x8 ahi = *(const bf16x8*)(Ah + off);
        bf16x8 alo = *(const bf16x8*)(Al + off);
        bf16x8 b0h = *(const bf16x8*)(Bh0 + off);
        bf16x8 b1h = *(const bf16x8*)(Bh1 + off);
        bf16x8 b2h = *(const bf16x8*)(Bh2 + off);
        bf16x8 b3h = *(const bf16x8*)(Bh3 + off);
        bf16x8 b0l = *(const bf16x8*)(Bl0 + off);
        bf16x8 b1l = *(const bf16x8*)(Bl1 + off);
        bf16x8 b2l = *(const bf16x8*)(Bl2 + off);
        bf16x8 b3l = *(const bf16x8*)(Bl3 + off);
        acc0 = __builtin_amdgcn_mfma_f32_16x16x32_bf16(ahi, b0h, acc0, 0, 0, 0);
        acc1 = __builtin_amdgcn_mfma_f32_16x16x32_bf16(ahi, b1h, acc1, 0, 0, 0);
        acc2 = __builtin_amdgcn_mfma_f32_16x16x32_bf16(ahi, b2h, acc2, 0, 0, 0);
        acc3 = __builtin_amdgcn_mfma_f32_16x16x32_bf16(ahi, b3h, acc3, 0, 0, 0);
        acc0 = __builtin_amdgcn_mfma_f32_16x16x32_bf16(alo, b0h, acc0, 0, 0, 0);
        acc1 = __builtin_amdgcn_mfma_f32_16x16x32_bf16(alo, b1h, acc1, 0, 0, 0);
        acc2 = __builtin_amdgcn_mfma_f32_16x16x32_bf16(alo, b2h, acc2, 0, 0, 0);
        acc3 = __builtin_amdgcn_mfma_f32_16x16x32_bf16(alo, b3h, acc3, 0, 0, 0);
        acc0 = __builtin_amdgcn_mfma_f32_16x16x32_bf16(ahi, b0l, acc0, 0, 0, 0);
        acc1 = __builtin_amdgcn_mfma_f32_16x16x32_bf16(ahi, b1l, acc1, 0, 0, 0);
        acc2 = __builtin_amdgcn_mfma_f32_16x16x32_bf16(ahi, b2l, acc2, 0, 0, 0);
        acc3 = __builtin_amdgcn_mfma_f32_16x16x32_bf16(ahi, b3l, acc3, 0, 0, 0);
    }

    int b = n0 >> 9;
    int nin = n0 & 511;
    #pragma unroll
    for (int r = 0; r < 4; ++r) {
        int fg = f0 + kg * 4 + r;
        size_t base = ((size_t)b * (NH * NF) + fg) * NN + nin + col;
        hpT[base +  0] = f2bf(acc0[r]);
        hpT[base + 16] = f2bf(acc1[r]);
        hpT[base + 32] = f2bf(acc2[r]);
        hpT[base + 48] = f2bf(acc3[r]);
    }
}

// ---------------- fused attention: softmax + MFMA PV over 4 heads -> f32 partial ----------------
// grid 1024: blockIdx.x = b*64 + itile*2 + half. 512 threads = 8 waves, 4 blocks/CU.
__global__ __launch_bounds__(512, 8) void attn_kernel(
    const unsigned short* __restrict__ hpT, const float* __restrict__ mb,
    const float* __restrict__ ssrc, const float* __restrict__ sdstT,
    float* __restrict__ part)
{
    __shared__ unsigned short P[16][520];     // 16.6 KB

    int bx = blockIdx.x;
    int half = bx & 1;
    int it = (bx >> 1) & 31;
    int b = bx >> 6;
    int i0 = it * 16;
    int tid = threadIdx.x;
    int lane = tid & 63, wave = tid >> 6;
    int col = lane & 15, kg = lane >> 4;

    f32x4 acc0 = {0.f,0.f,0.f,0.f}, acc1 = {0.f,0.f,0.f,0.f};

    for (int hq = 0; hq < 4; ++hq) {
        int head = half * 4 + hq;
        const float* sd = sdstT + (size_t)(b * NH + head) * NN;
        // ---- softmax: wave handles rows 2*wave, 2*wave+1; lane covers j=lane*8..+7 ----
        #pragma unroll
        for (int rr = 0; rr < 2; ++rr) {
            int i = wave * 2 + rr;
            int row = i0 + i;
            float s_i = ssrc[((size_t)(b * NN + row)) * NH + head];
            const float4* sd4 = (const float4*)(sd + lane * 8);
            const float4* mb4 = (const float4*)(mb + (size_t)row * NN + lane * 8);
            float4 sv0 = sd4[0], sv1 = sd4[1];
            float4 mv0 = mb4[0], mv1 = mb4[1];
            float p8[8];
            {
                float x;
                x = s_i + sv0.x; x = x > 0.f ? x : NEG_SLOPE * x; p8[0] = x + mv0.x;
                x = s_i + sv0.y; x = x > 0.f ? x : NEG_SLOPE * x; p8[1] = x + mv0.y;
                x = s_i + sv0.z; x = x > 0.f ? x : NEG_SLOPE * x; p8[2] = x + mv0.z;
                x = s_i + sv0.w; x = x > 0.f ? x : NEG_SLOPE * x; p8[3] = x + mv0.w;
                x = s_i + sv1.x; x = x > 0.f ? x : NEG_SLOPE * x; p8[4] = x + mv1.x;
                x = s_i + sv1.y; x = x > 0.f ? x : NEG_SLOPE * x; p8[5] = x + mv1.y;
                x = s_i + sv1.z; x = x > 0.f ? x : NEG_SLOPE * x; p8[6] = x + mv1.z;
                x = s_i + sv1.w; x = x > 0.f ? x : NEG_SLOPE * x; p8[7] = x + mv1.w;
            }
            float mx = fmaxf(fmaxf(fmaxf(p8[0], p8[1]), fmaxf(p8[2], p8[3])),
                             fmaxf(fmaxf(p8[4], p8[5]), fmaxf(p8[6], p8[7])));
            #pragma unroll
            for (int off = 32; off; off >>= 1) mx = fmaxf(mx, __shfl_xor(mx, off));
            float sum = 0.f;
            #pragma unroll
            for (int v = 0; v < 8; ++v) { p8[v] = __expf(p8[v] - mx); sum += p8[v]; }
            #pragma unroll
            for (int off = 32; off; off >>= 1) sum += __shfl_xor(sum, off);
            float rinv = 1.0f / sum;
            u16x8 pw;
            #pragma unroll
            for (int v = 0; v < 8; ++v) pw[v] = f2bf(p8[v] * rinv);
            *(u16x8*)&P[i][lane * 8] = pw;
        }
        __syncthreads();

        // ---- PV: wave = f-chunk; C[16 i][16 f], K=512, depth-2 B prefetch ----
        const unsigned short* Bp = hpT
            + ((size_t)(b * NH + head) * NF + wave * 16 + col) * NN + kg * 8;
        const unsigned short* Ap = &P[col][kg * 8];
        bf16x8 B0v = *(const bf16x8*)(Bp);
        bf16x8 B1v = *(const bf16x8*)(Bp + 32);
        #pragma unroll
        for (int ks = 0; ks < 8; ++ks) {
            bf16x8 a0 = *(const bf16x8*)(Ap + ks * 64);
            bf16x8 a1 = *(const bf16x8*)(Ap + ks * 64 + 32);
            bf16x8 nb0, nb1;
            if (ks < 7) {
                nb0 = *(const bf16x8*)(Bp + ks * 64 + 64);
                nb1 = *(const bf16x8*)(Bp + ks * 64 + 96);
            }
            acc0 = __builtin_amdgcn_mfma_f32_16x16x32_bf16(a0, B0v, acc0, 0, 0, 0);
            acc1 = __builtin_amdgcn_mfma_f32_16x16x32_bf16(a1, B1v, acc1, 0, 0, 0);
            if (ks < 7) { B0v = nb0; B1v = nb1; }
        }
        __syncthreads();
    }

    // ---- store partial: rows i = i0 + kg*4 + r, col f = wave*16 + (lane&15) ----
    float* po = part + (size_t)half * (NB * NN * NF);
    #pragma unroll
    for (int r = 0; r < 4; ++r) {
        po[((size_t)(b * NN + i0 + kg * 4 + r)) * NF + wave * 16 + col] = acc0[r] + acc1[r];
    }
}

// ---------------- combine halves, /8 ----------------
__global__ __launch_bounds__(256) void combine_kernel(
    const float* __restrict__ part, float* __restrict__ out)
{
    int t = blockIdx.x * 256 + threadIdx.x;   // over (B*N*F)/4
    float4 a = ((const float4*)part)[t];
    float4 c = ((const float4*)(part + (size_t)NB * NN * NF))[t];
    float4 o;
    o.x = (a.x + c.x) * 0.125f;
    o.y = (a.y + c.y) * 0.125f;
    o.z = (a.z + c.z) * 0.125f;
    o.w = (a.w + c.w) * 0.125f;
    ((float4*)out)[t] = o;
}

extern "C" void kernel_launch(void* const* d_in, const int* in_sizes, int n_in,
                              void* d_out, int out_size, void* d_ws, size_t ws_size,
                              hipStream_t stream)
{
    const float* h    = (const float*)d_in[0];
    const int*   adj  = (const int*)d_in[1];
    const float* bias = (const float*)d_in[2];
    const float* W    = (const float*)d_in[3];
    const float* a    = (const float*)d_in[4];
    float* out = (float*)d_out;

    char* ws = (char*)d_ws;
    unsigned short* hpT  = (unsigned short*)ws;                 ws += (size_t)NB * NH * NF * NN * 2;   // 16.78 MB
    float* mb    = (float*)ws;                                  ws += (size_t)NN * NN * 4;             // 1 MB
    float* ssrc  = (float*)ws;                                  ws += (size_t)NB * NN * NH * 4;
    float* sdstT = (float*)ws;                                  ws += (size_t)NB * NN * NH * 4;
    float* wasrc = (float*)ws;                                  ws += NH * NF * 4;
    float* wadst = (float*)ws;                                  ws += NH * NF * 4;
    unsigned short* hHi  = (unsigned short*)ws;                 ws += (size_t)NB * NN * NF * 2;        // 2 MB
    unsigned short* hLo  = (unsigned short*)ws;                 ws += (size_t)NB * NN * NF * 2;
    unsigned short* wtHi = (unsigned short*)ws;                 ws += (size_t)NH * NF * NF * 2;
    unsigned short* wtLo = (unsigned short*)ws;                 ws += (size_t)NH * NF * NF * 2;
    float* part  = (float*)ws;                                  ws += (size_t)2 * NB * NN * NF * 4;    // 8.4 MB

    hipLaunchKernelGGL(prep_kernel, dim3((NN * NN) / 256), dim3(256), 0, stream,
                       adj, bias, W, a, mb, wasrc, wadst);
    hipLaunchKernelGGL(split_kernel, dim3((NB * NN * NF + NH * NF * NF) / 256), dim3(256), 0, stream,
                       h, W, hHi, hLo, wtHi, wtLo);
    hipLaunchKernelGGL(score_kernel, dim3((NB * NN * NH) / 256), dim3(256), 0, stream,
                       h, wasrc, wadst, ssrc, sdstT);
    hipLaunchKernelGGL(hprime_kernel, dim3((NB * NN) / 64, (NH * NF) / 64), dim3(256), 0, stream,
                       hHi, hLo, wtHi, wtLo, hpT);
    hipLaunchKernelGGL(attn_kernel, dim3(NB * 32 * 2), dim3(512), 0, stream,
                       hpT, mb, ssrc, sdstT, part);
    hipLaunchKernelGGL(combine_kernel, dim3((NB * NN * NF / 4) / 256), dim3(256), 0, stream,
                       part, out);
}